// Round 11
// baseline (6116.436 us; speedup 1.0000x reference)
//
#include <hip/hip_runtime.h>
#include <hip/hip_bf16.h>
#include <stdint.h>

#define T_STEPS 256
#define HH      100
#define ROWS    8
#define BLK     512

typedef __bf16 bf16x8 __attribute__((ext_vector_type(8)));
typedef float  f32x4  __attribute__((ext_vector_type(4)));
typedef unsigned short ushort_t;

// A layout (R9/R10-verified): slot = ((mat*25 + mt)*4 + kt)*2 + part
// lane's 8 bf16 at slot*1024 + lane*16 = W_mat[mt*16+(lane&15)][kt*32+(lane>>4)*8+e]
// (0 if k>=100). part: 0=hi, 1=lo (exact bf16 residual split).
#define A_UNITS 38400
#define WS_B1   153600
#define WS_B2   154000
#define WS_WI   154400
#define WS_WL   154800
#define WS_BLIN 154900

__global__ __launch_bounds__(512) void pack_kernel(
    const float* __restrict__ Whh1, const float* __restrict__ Wih2,
    const float* __restrict__ Whh2,
    const float* __restrict__ bih1, const float* __restrict__ bhh1,
    const float* __restrict__ bih2, const float* __restrict__ bhh2,
    const float* __restrict__ Wih1, const float* __restrict__ Wlin,
    const float* __restrict__ blin, float* __restrict__ ws) {
  int idx = blockIdx.x * BLK + threadIdx.x;
  if (idx < A_UNITS) {
    int lane = idx & 63, slot = idx >> 6;
    int part = slot & 1, q = slot >> 1;
    int kt = q & 3, q2 = q >> 2;
    int mt = q2 % 25, mat = q2 / 25;
    const float* W = (mat == 0) ? Whh1 : (mat == 1) ? Wih2 : Whh2;
    int row = mt * 16 + (lane & 15);
    int kb  = kt * 32 + (lane >> 4) * 8;
    ushort_t* dst = (ushort_t*)ws + (size_t)slot * 512 + lane * 8;
#pragma unroll
    for (int e = 0; e < 8; ++e) {
      int k = kb + e;
      float w = (k < HH) ? W[row * HH + k] : 0.0f;
      __hip_bfloat16 hb = __float2bfloat16(w);
      ushort_t ub;
      if (part == 0) {
        __builtin_memcpy(&ub, &hb, 2);
      } else {
        float lo = w - __bfloat162float(hb);
        __hip_bfloat16 lb2 = __float2bfloat16(lo);
        __builtin_memcpy(&ub, &lb2, 2);
      }
      dst[e] = ub;
    }
  } else if (idx < A_UNITS + 1301) {
    int o = idx - A_UNITS;
    float v;
    if (o < 400)       v = bih1[o] + bhh1[o];
    else if (o < 800)  v = bih2[o - 400] + bhh2[o - 400];
    else if (o < 1200) v = Wih1[o - 800];
    else if (o < 1300) v = Wlin[o - 1200];
    else               v = blin[0];
    ws[WS_B1 + o] = v;
  }
}

__device__ __forceinline__ float sigf(float v) {
  return 1.0f / (1.0f + __expf(-v));
}
__device__ __forceinline__ float tanh_fast(float v) {
  float t = __expf(2.0f * v);
  return 1.0f - 2.0f / (t + 1.0f);
}

struct SM {
  ushort_t hB[4][2048];       // planes: 0=h1hi 1=h1lo 2=h2hi 3=h2lo; swizzled
  float gbp[8][404];
  float h2f[8][100];
  float b1s[400], b2s[400], wis[400], wls[100];
  float xall[8 * 256];
};

// lgkmcnt-only barrier: A-prefetch (vmcnt) rides across phases. Proven R7-R10.
#define BAR() do { asm volatile("s_waitcnt lgkmcnt(0)" ::: "memory"); \
                   __builtin_amdgcn_s_barrier(); } while (0)

// ---- pipeline macros (expand inside body<>, reference its locals) ----
#define LOADF(DST, MAT, IDX)                                              \
  do {                                                                    \
    const char* _p = Ab + (size_t)(((MAT)*25 + mtv[IDX]) * 8) * 1024 + lb;\
    _Pragma("unroll")                                                     \
    for (int f = 0; f < 4; ++f) {                                         \
      __builtin_memcpy(&DST[f],     _p + (2 * f) * 1024, 16);             \
      __builtin_memcpy(&DST[f + 4], _p + (2 * f + 1) * 1024, 16);         \
    }                                                                     \
  } while (0)

#define LOADB(HI, LO)                                                     \
  _Pragma("unroll")                                                       \
  for (int kt = 0; kt < 4; ++kt) {                                        \
    __builtin_memcpy(&bh[kt], &s->hB[HI][boff[kt]], 16);                  \
    __builtin_memcpy(&bl[kt], &s->hB[LO][boff[kt]], 16);                  \
  }

#define CONSUME(SRC, IDX, RMW)                                            \
  do {                                                                    \
    f32x4 q0 = {0, 0, 0, 0}, q1 = q0, q2 = q0;                            \
    _Pragma("unroll")                                                     \
    for (int kt = 0; kt < 4; ++kt) {                                      \
      q0 = __builtin_amdgcn_mfma_f32_16x16x32_bf16(SRC[kt], bh[kt], q0, 0, 0, 0); \
      q1 = __builtin_amdgcn_mfma_f32_16x16x32_bf16(SRC[kt], bl[kt], q1, 0, 0, 0); \
      q2 = __builtin_amdgcn_mfma_f32_16x16x32_bf16(SRC[kt + 4], bh[kt], q2, 0, 0, 0); \
    }                                                                     \
    if (brow < 8) {                                                       \
      f32x4 s_ = q0 + q1 + q2;                                            \
      float* gp = &s->gbp[brow][mtv[IDX] * 16 + gate0];                   \
      if (RMW) { f32x4 o_; __builtin_memcpy(&o_, gp, 16); s_ += o_; }     \
      __builtin_memcpy(gp, &s_, 16);                                      \
    }                                                                     \
  } while (0)

#define ACTPASS(ER, EN, WOF, CC, L2F, BIAS, XTERM, HP0, HP1)              \
  do {                                                                    \
    float g0 = s->gbp[ER][EN]       + BIAS[EN]       XTERM(EN);           \
    float g1 = s->gbp[ER][EN + 100] + BIAS[EN + 100] XTERM(EN + 100);     \
    float g2 = s->gbp[ER][EN + 200] + BIAS[EN + 200] XTERM(EN + 200);     \
    float g3 = s->gbp[ER][EN + 300] + BIAS[EN + 300] XTERM(EN + 300);     \
    float iv = sigf(g0), fv = sigf(g1), gv = tanh_fast(g2), ov = sigf(g3);\
    CC = fv * CC + iv * gv;                                               \
    float h = ov * tanh_fast(CC);                                         \
    if (L2F) s->h2f[ER][EN] = h;                                          \
    __hip_bfloat16 hb_ = __float2bfloat16(h);                             \
    ushort_t ub;                                                          \
    __builtin_memcpy(&ub, &hb_, 2);                                       \
    s->hB[HP0][WOF] = ub;                                                 \
    float lo_ = h - __bfloat162float(hb_);                                \
    __hip_bfloat16 lb_ = __float2bfloat16(lo_);                           \
    __builtin_memcpy(&ub, &lb_, 2);                                       \
    s->hB[HP1][WOF] = ub;                                                 \
  } while (0)

#define XT1_0(J) + s->wis[J] * xv0
#define XT1_1(J) + s->wis[J] * xv1
#define XT_NONE(J)

#define ACT1(T_)                                                          \
  do {                                                                    \
    float xv0 = s->xall[e0r * 256 + (T_)];                                \
    ACTPASS(e0r, e0n, wof0, c1a, 0, s->b1s, XT1_0, 0, 1);                 \
    if (a1) {                                                             \
      float xv1 = s->xall[e1r * 256 + (T_)];                              \
      ACTPASS(e1r, e1n, wof1, c1b, 0, s->b1s, XT1_1, 0, 1);               \
    }                                                                     \
  } while (0)

#define ACT2()                                                            \
  do {                                                                    \
    ACTPASS(e0r, e0n, wof0, c2a, 1, s->b2s, XT_NONE, 2, 3);               \
    if (a1) ACTPASS(e1r, e1n, wof1, c2b, 1, s->b2s, XT_NONE, 2, 3);       \
  } while (0)

// one timestep, ping-pong parity (FA = buffer holding group (0,0) at entry)
#define STEP3(FA, FB, T_)                                                 \
  do {                                                                    \
    LOADB(0, 1);                                                          \
    LOADF(FB, 0, 1); CONSUME(FA, 0, 0);                                   \
    LOADF(FA, 0, 2); CONSUME(FB, 1, 0);                                   \
    LOADF(FB, 1, 0); CONSUME(FA, 2, 0);                                   \
    BAR(); ACT1(T_); BAR();                                               \
    LOADB(0, 1);                                                          \
    LOADF(FA, 1, 1); CONSUME(FB, 0, 0);                                   \
    LOADF(FB, 1, 2); CONSUME(FA, 1, 0);                                   \
    LOADF(FA, 2, 0); CONSUME(FB, 2, 0);                                   \
    LOADB(2, 3);                                                          \
    LOADF(FB, 2, 1); CONSUME(FA, 0, 1);                                   \
    LOADF(FA, 2, 2); CONSUME(FB, 1, 1);                                   \
    LOADF(FB, 0, 0); CONSUME(FA, 2, 1);                                   \
    BAR(); ACT2(); BAR();                                                 \
  } while (0)

#define STEP4(FA, FB, T_)                                                 \
  do {                                                                    \
    LOADB(0, 1);                                                          \
    LOADF(FB, 0, 1); CONSUME(FA, 0, 0);                                   \
    LOADF(FA, 0, 2); CONSUME(FB, 1, 0);                                   \
    LOADF(FB, 0, 3); CONSUME(FA, 2, 0);                                   \
    LOADF(FA, 1, 0); CONSUME(FB, 3, 0);                                   \
    BAR(); ACT1(T_); BAR();                                               \
    LOADB(0, 1);                                                          \
    LOADF(FB, 1, 1); CONSUME(FA, 0, 0);                                   \
    LOADF(FA, 1, 2); CONSUME(FB, 1, 0);                                   \
    LOADF(FB, 1, 3); CONSUME(FA, 2, 0);                                   \
    LOADF(FA, 2, 0); CONSUME(FB, 3, 0);                                   \
    LOADB(2, 3);                                                          \
    LOADF(FB, 2, 1); CONSUME(FA, 0, 1);                                   \
    LOADF(FA, 2, 2); CONSUME(FB, 1, 1);                                   \
    LOADF(FB, 2, 3); CONSUME(FA, 2, 1);                                   \
    LOADF(FA, 0, 0); CONSUME(FB, 3, 1);                                   \
    BAR(); ACT2(); BAR();                                                 \
  } while (0)

template <int NMT>
__device__ __forceinline__ void body(SM* s, const char* Ab, int tid, int T) {
  const int wid = tid >> 6, lane = tid & 63;
  const int brow = lane & 15, bg = lane >> 4;
  const int gate0 = bg * 4;
  const int lb = lane * 16;
  int boff[4];
#pragma unroll
  for (int kt = 0; kt < 4; ++kt)
    boff[kt] = brow * 128 + ((((kt << 2) + bg) ^ (brow & 7)) << 3);
  int mtv[NMT];
#pragma unroll
  for (int i = 0; i < NMT; ++i) mtv[i] = (NMT == 4) ? 21 + i : 3 * wid + i;

  const int e0r = tid / 100, e0n = tid - e0r * 100;
  const int e1  = tid + 512;
  const int e1r = e1 / 100, e1n = e1 - e1r * 100;
  const bool a1 = (e1 < ROWS * HH);
  const int wof0 = e0r * 128 + (((e0n >> 3) ^ (e0r & 7)) << 3) + (e0n & 7);
  const int wof1 = e1r * 128 + (((e1n >> 3) ^ (e1r & 7)) << 3) + (e1n & 7);
  float c1a = 0.f, c1b = 0.f, c2a = 0.f, c2b = 0.f;

  bf16x8 F0[8], F1[8], bh[4], bl[4];
  LOADF(F0, 0, 0);   // prologue: group (mat0, idx0)

  if constexpr (NMT == 3) {
#pragma unroll 1
    for (int t = 0; t < T; t += 2) {   // 9 groups/step: parity via 2-step unroll
      STEP3(F0, F1, t);
      STEP3(F1, F0, t + 1);
    }
  } else {
#pragma unroll 1
    for (int t = 0; t < T; ++t) {      // 12 groups/step: parity-even
      STEP4(F0, F1, t);
    }
  }
}

__global__ __launch_bounds__(512) void lstm_persist(
    const float* __restrict__ x, const float* __restrict__ ws,
    float* __restrict__ out, int T) {
  __shared__ SM sm;
  const int tid = threadIdx.x;
  const int r0  = blockIdx.x * ROWS;

  // ---- init: zero hB (pads stay zero), consts, full x preload ----
  for (int i = tid; i < 4096; i += BLK) ((uint32_t*)sm.hB)[i] = 0u;
  if (tid < 400) {
    sm.b1s[tid] = ws[WS_B1 + tid];
    sm.b2s[tid] = ws[WS_B2 + tid];
    sm.wis[tid] = ws[WS_WI + tid];
  }
  if (tid < HH) sm.wls[tid] = ws[WS_WL + tid];
#pragma unroll
  for (int p = 0; p < 4; ++p) {
    int e = tid + BLK * p;                        // 0..2047
    sm.xall[e] = x[(size_t)r0 * T_STEPS + e];     // rows contiguous
  }
  __syncthreads();

  if ((tid >> 6) == 7) body<4>(&sm, (const char*)ws, tid, T);
  else                 body<3>(&sm, (const char*)ws, tid, T);

  // ---- output: out[r] = h2f[r]·wlin + blin (h2f visible after last BAR) ----
  {
    int row = tid >> 5, l32 = tid & 31;
    if (row < ROWS) {
      float p = 0.0f;
#pragma unroll
      for (int k = 0; k < 4; ++k) {
        int n = l32 + 32 * k;
        if (n < HH) p += sm.h2f[row][n] * sm.wls[n];
      }
#pragma unroll
      for (int off = 16; off > 0; off >>= 1) p += __shfl_down(p, off, 32);
      if (l32 == 0) out[r0 + row] = p + ws[WS_BLIN];
    }
  }
}

// ---------------- launcher ----------------
extern "C" void kernel_launch(void* const* d_in, const int* in_sizes, int n_in,
                              void* d_out, int out_size, void* d_ws, size_t ws_size,
                              hipStream_t stream) {
  const float* x    = (const float*)d_in[0];
  const float* Wih1 = (const float*)d_in[1];
  const float* Whh1 = (const float*)d_in[2];
  const float* bih1 = (const float*)d_in[3];
  const float* bhh1 = (const float*)d_in[4];
  const float* Wih2 = (const float*)d_in[5];
  const float* Whh2 = (const float*)d_in[6];
  const float* bih2 = (const float*)d_in[7];
  const float* bhh2 = (const float*)d_in[8];
  const float* Wlin = (const float*)d_in[9];
  const float* blin = (const float*)d_in[10];

  float* ws  = (float*)d_ws;
  float* out = (float*)d_out;

  const int B = in_sizes[0] / T_STEPS;   // 2048

  pack_kernel<<<(A_UNITS + 1301 + BLK - 1) / BLK, BLK, 0, stream>>>(
      Whh1, Wih2, Whh2, bih1, bhh1, bih2, bhh2, Wih1, Wlin, blin, ws);

  lstm_persist<<<B / ROWS, BLK, 0, stream>>>(x, ws, out, T_STEPS);
}